// Round 1
// baseline (99.631 us; speedup 1.0000x reference)
//
#include <hip/hip_runtime.h>
#include <hip/hip_bf16.h>
#include <math.h>

#define BB 64
#define CC 3
#define HH 384
#define WW 384

__global__ __launch_bounds__(256) void GeometricAugment_kernel(
    const float* __restrict__ x,
    const float* __restrict__ angles,
    const float* __restrict__ dx,
    const float* __restrict__ dy,
    float* __restrict__ out) {

    const int HW = HH * WW;
    int idx = blockIdx.x * blockDim.x + threadIdx.x;
    const int total = BB * HW;
    if (idx >= total) return;

    int b  = idx / HW;
    int p  = idx - b * HW;
    int yi = p / WW;
    int xi = p - yi * WW;

    const float cx = (WW - 1) * 0.5f;
    const float cy = (HH - 1) * 0.5f;

    float rad = angles[b] * (float)(M_PI / 180.0);
    float si, co;
    __sincosf(rad, &si, &co);
    float tx = dx[b];
    float ty = dy[b];

    float xo = (float)xi - cx - tx;
    float yo = (float)yi - cy - ty;

    float xs =  co * xo + si * yo + cx;
    float ys = -si * xo + co * yo + cy;

    float x0f = floorf(xs);
    float y0f = floorf(ys);
    float wx = xs - x0f;
    float wy = ys - y0f;
    int x0 = (int)x0f;
    int y0 = (int)y0f;
    int x1 = x0 + 1;
    int y1 = y0 + 1;

    // validity masks (zero padding outside)
    float vx0 = (x0 >= 0 && x0 < WW) ? 1.0f : 0.0f;
    float vx1 = (x1 >= 0 && x1 < WW) ? 1.0f : 0.0f;
    float vy0 = (y0 >= 0 && y0 < HH) ? 1.0f : 0.0f;
    float vy1 = (y1 >= 0 && y1 < HH) ? 1.0f : 0.0f;

    int x0c = min(max(x0, 0), WW - 1);
    int x1c = min(max(x1, 0), WW - 1);
    int y0c = min(max(y0, 0), HH - 1);
    int y1c = min(max(y1, 0), HH - 1);

    float w00 = (1.0f - wx) * (1.0f - wy) * vx0 * vy0;
    float w01 = wx * (1.0f - wy) * vx1 * vy0;
    float w10 = (1.0f - wx) * wy * vx0 * vy1;
    float w11 = wx * wy * vx1 * vy1;

    // base offsets for the 4 corners (channel 0)
    const float* imgb = x + (size_t)b * CC * HW;
    int o00 = y0c * WW + x0c;
    int o01 = y0c * WW + x1c;
    int o10 = y1c * WW + x0c;
    int o11 = y1c * WW + x1c;

    float* outb = out + (size_t)b * CC * HW + p;

    #pragma unroll
    for (int c = 0; c < CC; ++c) {
        const float* img = imgb + c * HW;
        float v00 = img[o00];
        float v01 = img[o01];
        float v10 = img[o10];
        float v11 = img[o11];
        float v = v00 * w00 + v01 * w01 + v10 * w10 + v11 * w11;
        v = fminf(fmaxf(v, 0.0f), 1.0f);
        outb[c * HW] = v;
    }
}

extern "C" void kernel_launch(void* const* d_in, const int* in_sizes, int n_in,
                              void* d_out, int out_size, void* d_ws, size_t ws_size,
                              hipStream_t stream) {
    const float* x      = (const float*)d_in[0];
    const float* angles = (const float*)d_in[1];
    const float* dx     = (const float*)d_in[2];
    const float* dy     = (const float*)d_in[3];
    float* out = (float*)d_out;

    const int total = BB * HH * WW;  // one thread per (b,y,x), covers C channels
    const int block = 256;
    const int grid = (total + block - 1) / block;
    GeometricAugment_kernel<<<grid, block, 0, stream>>>(x, angles, dx, dy, out);
}

// Round 2
// 89.135 us; speedup vs baseline: 1.1178x; 1.1178x over previous
//
#include <hip/hip_runtime.h>
#include <hip/hip_bf16.h>
#include <math.h>

#define BB 64
#define CC 3
#define HH 384
#define WW 384

// 2D tiling: each block = 64x32 output tile of one image.
// 256 threads as 64(x) x 4(y); each thread does 8 rows (stride 4).
#define TILE_W 64
#define TILE_H 32
#define TX_TILES (WW / TILE_W)   // 6
#define TY_TILES (HH / TILE_H)   // 12
#define TILES_PER_IMG (TX_TILES * TY_TILES)  // 72
#define NBLOCKS (BB * TILES_PER_IMG)         // 4608 (divisible by 8)

__global__ __launch_bounds__(256) void GeometricAugment_kernel(
    const float* __restrict__ x,
    const float* __restrict__ angles,
    const float* __restrict__ dx,
    const float* __restrict__ dy,
    float* __restrict__ out) {

    const int HW = HH * WW;

    // XCD-chunked bijective swizzle: 4608 blocks, 8 XCDs -> 576-chunks.
    int bid = blockIdx.x;
    int swz = (bid & 7) * (NBLOCKS / 8) + (bid >> 3);

    int b    = swz / TILES_PER_IMG;
    int t    = swz - b * TILES_PER_IMG;
    int tyb  = t / TX_TILES;
    int txb  = t - tyb * TX_TILES;

    int tid = threadIdx.x;
    int tx  = tid & 63;        // 0..63
    int tyl = tid >> 6;        // 0..3

    int x_out  = txb * TILE_W + tx;
    int y_base = tyb * TILE_H + tyl;

    const float cx = (WW - 1) * 0.5f;
    const float cy = (HH - 1) * 0.5f;

    float rad = angles[b] * (float)(M_PI / 180.0);
    float si, co;
    __sincosf(rad, &si, &co);
    float txs = dx[b];
    float tys = dy[b];

    float xo = (float)x_out - cx - txs;
    float yo = (float)y_base - cy - tys;

    // starting sample coords; per-row (y += 4) increments: xs += 4*si, ys += 4*co
    float xs =  co * xo + si * yo + cx;
    float ys = -si * xo + co * yo + cy;
    const float dxs = 4.0f * si;
    const float dys = 4.0f * co;

    const float* imgb = x + (size_t)b * CC * HW;
    float* outb = out + (size_t)b * CC * HW + (size_t)y_base * WW + x_out;

    #pragma unroll
    for (int r = 0; r < TILE_H / 4; ++r) {
        float x0f = floorf(xs);
        float y0f = floorf(ys);
        float wx = xs - x0f;
        float wy = ys - y0f;
        int x0 = (int)x0f;
        int y0 = (int)y0f;
        int x1 = x0 + 1;
        int y1 = y0 + 1;

        float vx0 = (x0 >= 0 && x0 < WW) ? 1.0f : 0.0f;
        float vx1 = (x1 >= 0 && x1 < WW) ? 1.0f : 0.0f;
        float vy0 = (y0 >= 0 && y0 < HH) ? 1.0f : 0.0f;
        float vy1 = (y1 >= 0 && y1 < HH) ? 1.0f : 0.0f;

        int x0c = min(max(x0, 0), WW - 1);
        int x1c = min(max(x1, 0), WW - 1);
        int y0c = min(max(y0, 0), HH - 1);
        int y1c = min(max(y1, 0), HH - 1);

        float w00 = (1.0f - wx) * (1.0f - wy) * vx0 * vy0;
        float w01 = wx * (1.0f - wy) * vx1 * vy0;
        float w10 = (1.0f - wx) * wy * vx0 * vy1;
        float w11 = wx * wy * vx1 * vy1;

        int o00 = y0c * WW + x0c;
        int o01 = y0c * WW + x1c;
        int o10 = y1c * WW + x0c;
        int o11 = y1c * WW + x1c;

        #pragma unroll
        for (int c = 0; c < CC; ++c) {
            const float* img = imgb + c * HW;
            float v00 = img[o00];
            float v01 = img[o01];
            float v10 = img[o10];
            float v11 = img[o11];
            float v = v00 * w00 + v01 * w01 + v10 * w10 + v11 * w11;
            v = fminf(fmaxf(v, 0.0f), 1.0f);
            __builtin_nontemporal_store(v, outb + (size_t)c * HW + (size_t)r * 4 * WW);
        }

        xs += dxs;
        ys += dys;
    }
}

extern "C" void kernel_launch(void* const* d_in, const int* in_sizes, int n_in,
                              void* d_out, int out_size, void* d_ws, size_t ws_size,
                              hipStream_t stream) {
    const float* x      = (const float*)d_in[0];
    const float* angles = (const float*)d_in[1];
    const float* dx     = (const float*)d_in[2];
    const float* dy     = (const float*)d_in[3];
    float* out = (float*)d_out;

    GeometricAugment_kernel<<<NBLOCKS, 256, 0, stream>>>(x, angles, dx, dy, out);
}

// Round 3
// 59.473 us; speedup vs baseline: 1.6752x; 1.4988x over previous
//
#include <hip/hip_runtime.h>
#include <hip/hip_bf16.h>
#include <math.h>

#define BB 64
#define CC 3
#define HH 384
#define WW 384
#define HW (HH * WW)

// Each block: 64x16 output tile of one image, staged via LDS.
#define TILE_W 64
#define TILE_H 16
#define TX_TILES (WW / TILE_W)                 // 6
#define TY_TILES (HH / TILE_H)                 // 24
#define TILES_PER_IMG (TX_TILES * TY_TILES)    // 144
#define NBLOCKS (BB * TILES_PER_IMG)           // 9216 (divisible by 8)

// Rotated bbox of a 64x16 tile at <=15deg:
//   x-span <= sqrt(63^2+15^2) = 64.8 -> floor-span 65; +1 (x1) +2 (margin) -> 69
//   y-span <= 63*sin15 + 15*cos15 = 30.8 -> floor-span 31; +1 +2 -> 35
#define LW_STRIDE 70
#define LH_MAX 36
// LDS = 3 * 36 * 70 * 4 = 30240 B -> 5 blocks/CU (20 waves)

__global__ __launch_bounds__(256) void GeometricAugment_kernel(
    const float* __restrict__ x,
    const float* __restrict__ angles,
    const float* __restrict__ dx,
    const float* __restrict__ dy,
    float* __restrict__ out) {

    __shared__ float lds[CC * LH_MAX * LW_STRIDE];

    // XCD-chunked bijective swizzle (9216 % 8 == 0)
    int bid = blockIdx.x;
    int swz = (bid & 7) * (NBLOCKS / 8) + (bid >> 3);

    int b   = swz / TILES_PER_IMG;
    int t   = swz - b * TILES_PER_IMG;
    int tyb = t / TX_TILES;
    int txb = t - tyb * TX_TILES;

    int tid = threadIdx.x;
    int tx  = tid & 63;   // 0..63
    int tyl = tid >> 6;   // 0..3

    const int X0 = txb * TILE_W;
    const int Y0 = tyb * TILE_H;

    const float cx = (WW - 1) * 0.5f;
    const float cy = (HH - 1) * 0.5f;

    float rad = angles[b] * (float)(M_PI / 180.0);
    float si, co;
    __sincosf(rad, &si, &co);
    float txs = dx[b];
    float tys = dy[b];

    // tile-corner sample coords (uniform across block)
    float xo0 = (float)X0 - cx - txs;
    float xo1 = (float)(X0 + TILE_W - 1) - cx - txs;
    float yo0 = (float)Y0 - cy - tys;
    float yo1 = (float)(Y0 + TILE_H - 1) - cy - tys;

    float xsA = co * xo0 + si * yo0 + cx;
    float xsB = co * xo1 + si * yo0 + cx;
    float xsC = co * xo0 + si * yo1 + cx;
    float xsD = co * xo1 + si * yo1 + cx;
    float ysA = -si * xo0 + co * yo0 + cy;
    float ysB = -si * xo1 + co * yo0 + cy;
    float ysC = -si * xo0 + co * yo1 + cy;
    float ysD = -si * xo1 + co * yo1 + cy;

    float xsmin = fminf(fminf(xsA, xsB), fminf(xsC, xsD));
    float xsmax = fmaxf(fmaxf(xsA, xsB), fmaxf(xsC, xsD));
    float ysmin = fminf(fminf(ysA, ysB), fminf(ysC, ysD));
    float ysmax = fmaxf(fmaxf(ysA, ysB), fmaxf(ysC, ysD));

    int ximin = (int)floorf(xsmin) - 1;
    int yimin = (int)floorf(ysmin) - 1;
    int LW = (int)floorf(xsmax) + 2 - ximin + 1;  // <= 69
    int LH = (int)floorf(ysmax) + 2 - yimin + 1;  // <= 35
    LW = min(LW, LW_STRIDE);
    LH = min(LH, LH_MAX);

    const float* imgb = x + (size_t)b * CC * HW;

    // ---- stage bbox into LDS (coalesced rows, clamped addressing) ----
    for (int y = tyl; y < LH; y += 4) {
        int gy = min(max(yimin + y, 0), HH - 1);
        const float* row = imgb + gy * WW;
        for (int xL = tx; xL < LW; xL += 64) {
            int gx = min(max(ximin + xL, 0), WW - 1);
            #pragma unroll
            for (int c = 0; c < CC; ++c) {
                lds[(c * LH_MAX + y) * LW_STRIDE + xL] = row[c * HW + gx];
            }
        }
    }
    __syncthreads();

    // ---- gather from LDS ----
    int x_out = X0 + tx;
    float xo = (float)x_out - cx - txs;

    float* outb = out + (size_t)b * CC * HW + (size_t)Y0 * WW + x_out;

    #pragma unroll
    for (int r = 0; r < TILE_H / 4; ++r) {
        int y_out = Y0 + tyl + r * 4;
        float yo = (float)y_out - cy - tys;

        float xs =  co * xo + si * yo + cx;
        float ys = -si * xo + co * yo + cy;

        float x0f = floorf(xs);
        float y0f = floorf(ys);
        float wx = xs - x0f;
        float wy = ys - y0f;
        int x0 = (int)x0f;
        int y0 = (int)y0f;
        int x1 = x0 + 1;
        int y1 = y0 + 1;

        float vx0 = (x0 >= 0 && x0 < WW) ? 1.0f : 0.0f;
        float vx1 = (x1 >= 0 && x1 < WW) ? 1.0f : 0.0f;
        float vy0 = (y0 >= 0 && y0 < HH) ? 1.0f : 0.0f;
        float vy1 = (y1 >= 0 && y1 < HH) ? 1.0f : 0.0f;

        float w00 = (1.0f - wx) * (1.0f - wy) * vx0 * vy0;
        float w01 = wx * (1.0f - wy) * vx1 * vy0;
        float w10 = (1.0f - wx) * wy * vx0 * vy1;
        float w11 = wx * wy * vx1 * vy1;

        int xL0 = x0 - ximin;   // in [1, LW-2] by construction
        int yL0 = y0 - yimin;

        int base = yL0 * LW_STRIDE + xL0;

        #pragma unroll
        for (int c = 0; c < CC; ++c) {
            const float* l = lds + c * LH_MAX * LW_STRIDE + base;
            float v00 = l[0];
            float v01 = l[1];
            float v10 = l[LW_STRIDE];
            float v11 = l[LW_STRIDE + 1];
            float v = v00 * w00 + v01 * w01 + v10 * w10 + v11 * w11;
            v = fminf(fmaxf(v, 0.0f), 1.0f);
            __builtin_nontemporal_store(v, outb + (size_t)c * HW + (size_t)(tyl + r * 4) * WW);
        }
    }
}

extern "C" void kernel_launch(void* const* d_in, const int* in_sizes, int n_in,
                              void* d_out, int out_size, void* d_ws, size_t ws_size,
                              hipStream_t stream) {
    const float* x      = (const float*)d_in[0];
    const float* angles = (const float*)d_in[1];
    const float* dx     = (const float*)d_in[2];
    const float* dy     = (const float*)d_in[3];
    float* out = (float*)d_out;

    GeometricAugment_kernel<<<NBLOCKS, 256, 0, stream>>>(x, angles, dx, dy, out);
}